// Round 3
// baseline (168.412 us; speedup 1.0000x reference)
//
#include <hip/hip_runtime.h>

#define CAR 8
#define SROW 520   // CAR + 64*CAR
#define HID 256
#define EOUT 257
#define XPAD 288   // padded Q-input row: 8 self + 257 enc + pad, 9 k-steps of 32
#define ADIM 30

typedef __attribute__((ext_vector_type(8))) short sh8;
typedef __attribute__((ext_vector_type(4))) float f32x4;
typedef __attribute__((ext_vector_type(16))) float f32x16;

__device__ __forceinline__ short f2bf(float f) {
  unsigned u = __builtin_bit_cast(unsigned, f);
  u += 0x7fffu + ((u >> 16) & 1u);   // RNE
  return (short)(u >> 16);
}
// pack two fp32 -> packed bf16x2 (RNE, 5 VALU)
__device__ __forceinline__ unsigned f2bf2(float a, float b) {
  unsigned ua = __builtin_bit_cast(unsigned, a);
  ua += 0x7fffu + ((ua >> 16) & 1u);
  unsigned ub = __builtin_bit_cast(unsigned, b);
  ub += 0x7fffu + ((ub >> 16) & 1u);
  return __builtin_amdgcn_perm(ub, ua, 0x07060302);  // [a.hi16 | b.hi16]
}
// pack two fp32 -> packed bf16x2 (TRUNC, 1 VALU) — used for h staging only
__device__ __forceinline__ unsigned pkt(float a, float b) {
  return __builtin_amdgcn_perm(__builtin_bit_cast(unsigned, b),
                               __builtin_bit_cast(unsigned, a), 0x07060302);
}

// ---------------------------------------------------------------------------
// Prep: swizzle all weights to bf16 MFMA fragments.
// w1f  : [W1;b1]^T as 16x16x32 A  [16 mt][64][8]                     (8192)
// w2f32: W2 cols 0..255 as 32x32x16 B [16 ks][8 nt][64][8]           (65536)
//        B[k][n]: n = nt*32 + (l&31), k = ks*16 + (l>>5)*8 + j
// wt8  : W2 col 256 as 16x16x32 B [8 ks32][64][8] (cols 257.. -> 0)  (4096)
// w3f  : Qw1 as 16x16x32 B [9 ks][16 nt][64][8], k=X-row idx         (73728)
// wq2f : Qw2 as 16x16x32 B [8 ks][2 nt][64][8]                       (8192)
// ---------------------------------------------------------------------------
__global__ void k_prep(const float* __restrict__ W1, const float* __restrict__ b1,
                       const float* __restrict__ W2,
                       const float* __restrict__ Qw1, const float* __restrict__ Qw2,
                       short* __restrict__ w1f, short* __restrict__ w2f32,
                       short* __restrict__ wt8,
                       short* __restrict__ w3f, short* __restrict__ wq2f) {
  int idx = blockIdx.x * 256 + threadIdx.x;
  if (idx < 8192) {                         // [W1;b1]^T as 16x16 A
    int mt = idx >> 9, r = idx & 511, lane = r >> 3, j = r & 7;
    int quad = lane >> 4, m = lane & 15;
    int hid = mt * 16 + m;
    float v = (quad == 0) ? W1[j * HID + hid]
            : (quad == 1 && j == 0) ? b1[hid] : 0.0f;   // k=8 row = b1
    w1f[idx] = f2bf(v);
    return;
  }
  int i2 = idx - 8192;
  if (i2 < 65536) {                         // W2 as 32x32x16 B
    int ks = i2 >> 12, r = i2 & 4095;
    int nt = r >> 9, r2 = r & 511, l = r2 >> 3, j = r2 & 7;
    int k = ks * 16 + (l >> 5) * 8 + j;     // k < 256
    int n = nt * 32 + (l & 31);             // n < 256 < EOUT
    w2f32[i2] = f2bf(W2[k * EOUT + n]);
    return;
  }
  int i3 = i2 - 65536;
  if (i3 < 4096) {                          // col-256 tile as 16x16x32 B
    int ks32 = i3 >> 9, r2 = i3 & 511, l = r2 >> 3, j = r2 & 7;
    int n = 256 + (l & 15);
    int k = ks32 * 32 + ((l >> 4) & 3) * 8 + j;
    wt8[i3] = (n < EOUT) ? f2bf(W2[k * EOUT + n]) : (short)0;
    return;
  }
  int i4 = i3 - 4096;
  if (i4 < 73728) {                         // Qw1 as B (k indexes padded X row)
    int ks = i4 >> 13, r = i4 & 8191;
    int nt = r >> 9, r2 = r & 511, lane = r2 >> 3, j = r2 & 7;
    int quad = lane >> 4, m = lane & 15;
    int k = ks * 32 + quad * 8 + j, n = nt * 16 + m;
    float v = (k < 265) ? Qw1[k * HID + n] : 0.0f;
    w3f[i4] = f2bf(v);
    return;
  }
  int i5 = i4 - 73728;
  if (i5 < 8192) {                          // Qw2 as B
    int ks = i5 >> 10, r = i5 & 1023;
    int nt = r >> 9, r2 = r & 511, lane = r2 >> 3, j = r2 & 7;
    int quad = lane >> 4, m = lane & 15;
    int k = ks * 32 + quad * 8 + j, n = nt * 16 + m;
    float v = (n < ADIM) ? Qw2[k * ADIM + n] : 0.0f;
    wq2f[i5] = f2bf(v);
  }
}

// ---------------------------------------------------------------------------
// K1: fused encoder + pool. NB=2 elems, 8 waves (512 thr), phase 2 in 32x32.
// Rationale (R2 post-mortem): lgkm pipe was the top resource (~55us/CU) at
// 16x16 (1KB operands / 16.4kFLOP). 32x32x16 halves operand bytes per FLOP:
// per wave: 40 ds_read_b128 (was 72), 72 MFMA (64x 32x32 + 8x 16x16 col-256).
// Phase 1 identical to verified R2 except staging dest = 32x32 A-frag layout:
//   hlds32[c][ks16][lane][j]; c = agent-tile combo (e*2 + a>>5),
//   element = h[agent = c*32 + (lane&31)][hid = ks16*16 + (lane>>5)*8 + j].
// Phase 2: wave (e = w>>2, np = w&3): acc tiles [mt32 0,1] x [nt 2np,2np+1],
// per ks: 2 LDS A + 2 L2 B -> 4 MFMA. Pool: sum 16 regs + shfl_xor(32).
// ---------------------------------------------------------------------------
__global__ __launch_bounds__(512, 4)
void k_enc(const float* __restrict__ s, const short* __restrict__ w1f,
           const short* __restrict__ w2f32, const short* __restrict__ wt8,
           const float* __restrict__ b2, float* __restrict__ so288, int B) {
  __shared__ __align__(16) short hlds32[32768];  // 64 KB: [c][ks16][lane][j]
  __shared__ float ninvp[8];
  __shared__ float red8[8];

  const int tid = threadIdx.x;
  const int w = tid >> 6, lane = tid & 63;
  const int q = lane >> 4, m = lane & 15;
  const int we = w >> 2, g = w & 3;
  const size_t bg0 = 2 * (size_t)blockIdx.x;
  size_t bg = bg0 + we; if (bg >= (size_t)B) bg = B - 1;

  // ---- phase 1: h = relu([surr,1]@[W1;b1]) for agents 16g..16g+15 of elem we
  const float* srow0 = s + bg * SROW + CAR;
  int4 pk = {0, 0, 0, 0};
  bool inv = false;
  if (lane < 16) {                           // agent = 16*g + lane
    const float* sr = srow0 + (g * 16 + lane) * CAR;
    float4 f0 = ((const float4*)sr)[0], f1 = ((const float4*)sr)[1];
    inv = (f0.x == -1.f) | (f0.y == -1.f) | (f0.z == -1.f) | (f0.w == -1.f) |
          (f1.x == -1.f) | (f1.y == -1.f) | (f1.z == -1.f) | (f1.w == -1.f);
    if (!inv) {                              // mask folded at source
      pk.x = (int)f2bf2(f0.x, f0.y); pk.y = (int)f2bf2(f0.z, f0.w);
      pk.z = (int)f2bf2(f1.x, f1.y); pk.w = (int)f2bf2(f1.z, f1.w);
    }
  }
  const float vflag = inv ? 0.f : 1.f;
  unsigned long long bal = __ballot(inv);
  if (lane == 0) ninvp[w] = (float)__popcll(bal);

  if (w == 1 || w == 2) {                    // self-state + tail pad per elem
    size_t rr = bg0 + (w - 1); if (rr >= (size_t)B) rr = B - 1;
    if (lane < CAR)       so288[rr * XPAD + lane] = s[rr * SROW + lane];
    else if (lane < 16)   so288[rr * XPAD + 280 + (lane - 8)] = 0.f;
  }

  int4 p0;
  p0.x = __shfl(pk.x, m, 64); p0.y = __shfl(pk.y, m, 64);
  p0.z = __shfl(pk.z, m, 64); p0.w = __shfl(pk.w, m, 64);
  const float vv0 = __shfl(vflag, m, 64);
  if (q == 1) {                              // k=8 constant-1 column (masked)
    p0.x = (vv0 != 0.f) ? 0x3f80 : 0; p0.y = p0.z = p0.w = 0;
  } else if (q >= 2) {
    p0.x = p0.y = p0.z = p0.w = 0;
  }
  sh8 bs = __builtin_bit_cast(sh8, p0);

  // staging dest (32x32 A-frag layout), derived from 16x16 D layout:
  // hid = mt*16 + q*4 + r -> ks16 = mt, oct = q>>1, j = (q&1)*4 + r
  const int cI  = 2 * we + (g >> 1);
  const int lpw = (g & 1) * 16 + m + 32 * (q >> 1);
  const int j0  = (q & 1) * 4;
#pragma unroll 4
  for (int mt = 0; mt < 16; ++mt) {
    sh8 af = *(const sh8*)(w1f + (mt * 64 + lane) * 8);
    f32x4 z = {0.f, 0.f, 0.f, 0.f};
    f32x4 c0 = __builtin_amdgcn_mfma_f32_16x16x32_bf16(af, bs, z, 0, 0, 0);
    uint2 k0;
    k0.x = pkt(fmaxf(c0[0], 0.f), fmaxf(c0[1], 0.f));
    k0.y = pkt(fmaxf(c0[2], 0.f), fmaxf(c0[3], 0.f));
    *(uint2*)(&hlds32[((cI * 16 + mt) * 64 + lpw) * 8 + j0]) = k0;
  }
  __syncthreads();

  // ---- phase 2: enc = h @ W2 in 32x32x16 ----
  f32x16 z16;
#pragma unroll
  for (int r = 0; r < 16; ++r) z16[r] = 0.f;
  f32x16 acc00 = z16, acc01 = z16, acc10 = z16, acc11 = z16;

  const int c0i = 2 * we, c1i = 2 * we + 1;
  const int nt0 = 2 * g, nt1 = 2 * g + 1;
#pragma unroll
  for (int ks = 0; ks < 16; ++ks) {
    sh8 A0 = *(const sh8*)(&hlds32[((c0i * 16 + ks) * 64 + lane) * 8]);
    sh8 A1 = *(const sh8*)(&hlds32[((c1i * 16 + ks) * 64 + lane) * 8]);
    sh8 B0 = *(const sh8*)(w2f32 + ((ks * 8 + nt0) * 64 + lane) * 8);
    sh8 B1 = *(const sh8*)(w2f32 + ((ks * 8 + nt1) * 64 + lane) * 8);
    acc00 = __builtin_amdgcn_mfma_f32_32x32x16_bf16(A0, B0, acc00, 0, 0, 0);
    acc10 = __builtin_amdgcn_mfma_f32_32x32x16_bf16(A1, B0, acc10, 0, 0, 0);
    acc01 = __builtin_amdgcn_mfma_f32_32x32x16_bf16(A0, B1, acc01, 0, 0, 0);
    acc11 = __builtin_amdgcn_mfma_f32_32x32x16_bf16(A1, B1, acc11, 0, 0, 0);
  }

  // col-256 tile: 16x16x32, agents 16*np..16*np+15 of elem we
  f32x4 acc8 = {0.f, 0.f, 0.f, 0.f};
  const int c8  = 2 * we + (g >> 1);
  const int lp8 = (g & 1) * 16 + (lane & 15) + 32 * ((lane >> 4) & 1);
  const int kof = lane >> 5;
#pragma unroll
  for (int ks32 = 0; ks32 < 8; ++ks32) {
    sh8 A8 = *(const sh8*)(&hlds32[((c8 * 16 + 2 * ks32 + kof) * 64 + lp8) * 8]);
    sh8 B8 = *(const sh8*)(wt8 + (ks32 * 64 + lane) * 8);
    acc8 = __builtin_amdgcn_mfma_f32_16x16x32_bf16(A8, B8, acc8, 0, 0, 0);
  }

  // ---- phase 3: relu + masked pool ----
  const float ninv_e = ninvp[4 * we] + ninvp[4 * we + 1] +
                       ninvp[4 * we + 2] + ninvp[4 * we + 3];
  size_t rr = bg0 + we; if (rr >= (size_t)B) rr = B - 1;
  {
    const int col = nt0 * 32 + (lane & 31);  // 0..255
    const float b2c = b2[col];
    float ssum = 0.f;
#pragma unroll
    for (int r = 0; r < 16; ++r)
      ssum += fmaxf(acc00[r] + b2c, 0.f) + fmaxf(acc10[r] + b2c, 0.f);
    ssum += __shfl_xor(ssum, 32, 64);        // complementary row halves
    ssum -= ninv_e * fmaxf(b2c, 0.f);        // invalid agents: relu(b2)
    if (lane < 32) so288[rr * XPAD + CAR + col] = ssum;
  }
  {
    const int col = nt1 * 32 + (lane & 31);
    const float b2c = b2[col];
    float ssum = 0.f;
#pragma unroll
    for (int r = 0; r < 16; ++r)
      ssum += fmaxf(acc01[r] + b2c, 0.f) + fmaxf(acc11[r] + b2c, 0.f);
    ssum += __shfl_xor(ssum, 32, 64);
    ssum -= ninv_e * fmaxf(b2c, 0.f);
    if (lane < 32) so288[rr * XPAD + CAR + col] = ssum;
  }
  // col-256 pool: per-wave 16-agent partial, cross-wave via red8
  {
    const int n8 = lane & 15;
    const float b8c = (n8 == 0) ? b2[256] : 0.f;
    float s8 = 0.f;
#pragma unroll
    for (int r = 0; r < 4; ++r) s8 += fmaxf(acc8[r] + b8c, 0.f);
    s8 += __shfl_xor(s8, 16, 64);
    s8 += __shfl_xor(s8, 32, 64);
    if (lane == 0) red8[w] = s8;
  }
  __syncthreads();
  if ((w == 0 || w == 4) && lane < 16) {     // wave 0 -> elem 0, wave 4 -> elem 1
    const int e2 = w >> 2;
    size_t rr2 = bg0 + e2; if (rr2 >= (size_t)B) rr2 = B - 1;
    float v = 0.f;
    if (lane == 0) {
      const float ninv2 = ninvp[4 * e2] + ninvp[4 * e2 + 1] +
                          ninvp[4 * e2 + 2] + ninvp[4 * e2 + 3];
      v = red8[4 * e2] + red8[4 * e2 + 1] + red8[4 * e2 + 2] + red8[4 * e2 + 3]
        - ninv2 * fmaxf(b2[256], 0.f);
    }
    so288[rr2 * XPAD + CAR + 256 + lane] = v;  // lanes 1..15 zero cols 257..271
  }
}

// ---------------------------------------------------------------------------
// K2: Q-head, MFMA. 4 waves, 32 batch rows per block (unchanged, ~13 us).
// ---------------------------------------------------------------------------
__global__ __launch_bounds__(256, 2)
void k_q(const float* __restrict__ so288, const short* __restrict__ w3f,
         const float* __restrict__ Qb1, const short* __restrict__ wq2f,
         const float* __restrict__ Qb2, float* __restrict__ out, int B) {
  __shared__ __align__(16) short xf[2 * 9 * 64 * 8];  // 36 KB, [mt][ks][lane][j]
  __shared__ __align__(16) float H[32 * 260];          // 33.3 KB
  const int tid = threadIdx.x;
  const int w = tid >> 6, lane = tid & 63;
  const int q = lane >> 4, m = lane & 15;
  const int b0 = blockIdx.x * 32;

  // ---- stage X ----
#pragma unroll
  for (int it = 0; it < 5; ++it) {
    int sidx = tid + it * 256;               // = (mt*9+ks)*64 + l
    if (sidx < 1152) {
      int mt = sidx / 576, rem = sidx % 576;
      int ks = rem >> 6, l = rem & 63;
      int lq = l >> 4, lm = l & 15;
      int row = b0 + mt * 16 + lm; if (row >= B) row = B - 1;
      const float* xp = so288 + (size_t)row * XPAD + ks * 32 + lq * 8;
      float4 xa = ((const float4*)xp)[0], xb = ((const float4*)xp)[1];
      int4 t = {(int)f2bf2(xa.x, xa.y), (int)f2bf2(xa.z, xa.w),
                (int)f2bf2(xb.x, xb.y), (int)f2bf2(xb.z, xb.w)};
      *(int4*)(xf + sidx * 8) = t;
    }
  }
  __syncthreads();

  // ---- GEMM1: X(32x288) @ Qw1 -> H ----
  f32x4 acc1[2][4];
#pragma unroll
  for (int mt = 0; mt < 2; ++mt)
#pragma unroll
    for (int i = 0; i < 4; ++i) {
      f32x4 z = {0.f, 0.f, 0.f, 0.f};
      acc1[mt][i] = z;
    }
#pragma unroll
  for (int ks = 0; ks < 9; ++ks) {
    sh8 A0 = *(const sh8*)(xf + ((0 * 9 + ks) * 64 + lane) * 8);
    sh8 A1 = *(const sh8*)(xf + ((1 * 9 + ks) * 64 + lane) * 8);
#pragma unroll
    for (int i = 0; i < 4; ++i) {
      sh8 Bf = *(const sh8*)(w3f + ((ks * 16 + 4 * w + i) * 64 + lane) * 8);
      acc1[0][i] = __builtin_amdgcn_mfma_f32_16x16x32_bf16(A0, Bf, acc1[0][i], 0, 0, 0);
      acc1[1][i] = __builtin_amdgcn_mfma_f32_16x16x32_bf16(A1, Bf, acc1[1][i], 0, 0, 0);
    }
  }
#pragma unroll
  for (int i = 0; i < 4; ++i) {
    const int hcol = (4 * w + i) * 16 + m;
    const float bq = Qb1[hcol];
#pragma unroll
    for (int mt = 0; mt < 2; ++mt)
#pragma unroll
      for (int r = 0; r < 4; ++r)
        H[(mt * 16 + q * 4 + r) * 260 + hcol] = fmaxf(acc1[mt][i][r] + bq, 0.f);
  }
  __syncthreads();

  // ---- GEMM2: H(32x256) @ Qw2 -> out ----
  const int mt2 = w >> 1, nt2 = w & 1;
  f32x4 acc2 = {0.f, 0.f, 0.f, 0.f};
#pragma unroll
  for (int ks = 0; ks < 8; ++ks) {
    const float* hp = H + (mt2 * 16 + m) * 260 + ks * 32 + q * 8;
    float4 ha = ((const float4*)hp)[0], hb = ((const float4*)hp)[1];
    int4 t = {(int)f2bf2(ha.x, ha.y), (int)f2bf2(ha.z, ha.w),
              (int)f2bf2(hb.x, hb.y), (int)f2bf2(hb.z, hb.w)};
    sh8 A2 = __builtin_bit_cast(sh8, t);
    sh8 Bf = *(const sh8*)(wq2f + ((ks * 2 + nt2) * 64 + lane) * 8);
    acc2 = __builtin_amdgcn_mfma_f32_16x16x32_bf16(A2, Bf, acc2, 0, 0, 0);
  }
  const int act = nt2 * 16 + m;
  if (act < ADIM) {
    const float bq = Qb2[act];
#pragma unroll
    for (int r = 0; r < 4; ++r) {
      const int row = b0 + mt2 * 16 + q * 4 + r;
      if (row < B) out[(size_t)row * ADIM + act] = acc2[r] + bq;
    }
  }
}

extern "C" void kernel_launch(void* const* d_in, const int* in_sizes, int n_in,
                              void* d_out, int out_size, void* d_ws, size_t ws_size,
                              hipStream_t stream) {
  const float* s   = (const float*)d_in[0];
  const float* W1  = (const float*)d_in[1];
  const float* b1  = (const float*)d_in[2];
  const float* W2  = (const float*)d_in[3];
  const float* b2  = (const float*)d_in[4];
  const float* Qw1 = (const float*)d_in[5];
  const float* Qb1 = (const float*)d_in[6];
  const float* Qw2 = (const float*)d_in[7];
  const float* Qb2 = (const float*)d_in[8];
  float* out = (float*)d_out;
  const int B = in_sizes[0] / SROW;

  // ws: [so288: B*288 f32][w1f 8192][w2f32 65536][wt8 4096][w3f 73728][wq2f 8192]
  char* wsb = (char*)d_ws;
  float* so288 = (float*)wsb;
  size_t off = (size_t)B * XPAD * sizeof(float);
  short* w1f   = (short*)(wsb + off);           off += 8192 * 2;
  short* w2f32 = (short*)(wsb + off);           off += 65536 * 2;
  short* wt8   = (short*)(wsb + off);           off += 4096 * 2;
  short* w3f   = (short*)(wsb + off);           off += 73728 * 2;
  short* wq2f  = (short*)(wsb + off);

  const int prep_elems = 8192 + 65536 + 4096 + 73728 + 8192;
  k_prep<<<(prep_elems + 255) / 256, 256, 0, stream>>>(W1, b1, W2, Qw1, Qw2,
                                                       w1f, w2f32, wt8, w3f, wq2f);
  k_enc<<<(B + 1) / 2, 512, 0, stream>>>(s, w1f, w2f32, wt8, b2, so288, B);
  k_q<<<(B + 31) / 32, 256, 0, stream>>>(so288, w3f, Qb1, wq2f, Qb2, out, B);
}

// Round 4
// 167.554 us; speedup vs baseline: 1.0051x; 1.0051x over previous
//
#include <hip/hip_runtime.h>

#define CAR 8
#define SROW 520   // CAR + 64*CAR
#define HID 256
#define EOUT 257
#define XPAD 288   // padded Q-input row: 8 self + 257 enc + pad, 9 k-steps of 32
#define ADIM 30

typedef __attribute__((ext_vector_type(8))) short sh8;
typedef __attribute__((ext_vector_type(4))) float f32x4;

__device__ __forceinline__ short f2bf(float f) {
  unsigned u = __builtin_bit_cast(unsigned, f);
  u += 0x7fffu + ((u >> 16) & 1u);   // RNE
  return (short)(u >> 16);
}
// pack two fp32 -> packed bf16x2 (RNE, 5 VALU)
__device__ __forceinline__ unsigned f2bf2(float a, float b) {
  unsigned ua = __builtin_bit_cast(unsigned, a);
  ua += 0x7fffu + ((ua >> 16) & 1u);
  unsigned ub = __builtin_bit_cast(unsigned, b);
  ub += 0x7fffu + ((ub >> 16) & 1u);
  return __builtin_amdgcn_perm(ub, ua, 0x07060302);  // [a.lo16pos | b.hi16pos]
}
// pack two fp32 -> packed bf16x2 (TRUNC, 1 VALU) — used for h staging only
__device__ __forceinline__ unsigned pkt(float a, float b) {
  return __builtin_amdgcn_perm(__builtin_bit_cast(unsigned, b),
                               __builtin_bit_cast(unsigned, a), 0x07060302);
}

// ---------------------------------------------------------------------------
// Prep: swizzle all weights to bf16 MFMA fragments.
// w1f : [W1;b1]^T as 16x16x32 A [16 mt][64][8]  k=0..7 W1 row, k=8 b1  (8192)
// w2f : [W2;b2] as 16x16x32 B [9 ks][17 nt][64][8], stride/ks = 8704
//       k<256 -> W2 row k; k==256 -> b2 (bias folded into K); k>256 -> 0
//       (78336)
// w3f : Qw1 as 16x16x32 B [9 ks][16 nt][64][8], k=X-row idx            (73728)
// wq2f: Qw2 as 16x16x32 B [8 ks][2 nt][64][8]                          (8192)
// ---------------------------------------------------------------------------
__global__ void k_prep(const float* __restrict__ W1, const float* __restrict__ b1,
                       const float* __restrict__ W2, const float* __restrict__ b2,
                       const float* __restrict__ Qw1, const float* __restrict__ Qw2,
                       short* __restrict__ w1f, short* __restrict__ w2f,
                       short* __restrict__ w3f, short* __restrict__ wq2f) {
  int idx = blockIdx.x * 256 + threadIdx.x;
  if (idx < 8192) {                         // [W1;b1]^T as A
    int mt = idx >> 9, r = idx & 511, lane = r >> 3, j = r & 7;
    int quad = lane >> 4, m = lane & 15;
    int hid = mt * 16 + m;
    float v = (quad == 0) ? W1[j * HID + hid]
            : (quad == 1 && j == 0) ? b1[hid] : 0.0f;   // k=8 row = b1
    w1f[idx] = f2bf(v);
    return;
  }
  int i2 = idx - 8192;
  if (i2 < 78336) {                         // [W2;b2] as B (9 ks, stride 8704)
    int ks = i2 / 8704, r = i2 % 8704;
    int nt = r >> 9, r2 = r & 511, lane = r2 >> 3, j = r2 & 7;
    int quad = lane >> 4, m = lane & 15;
    int k = ks * 32 + quad * 8 + j, n = nt * 16 + m;
    float v = 0.0f;
    if (n < EOUT) {
      if (k < 256)       v = W2[k * EOUT + n];
      else if (k == 256) v = b2[n];          // bias row
    }
    w2f[i2] = f2bf(v);
    return;
  }
  int i3 = i2 - 78336;
  if (i3 < 73728) {                         // Qw1 as B (k indexes padded X row)
    int ks = i3 >> 13, r = i3 & 8191;
    int nt = r >> 9, r2 = r & 511, lane = r2 >> 3, j = r2 & 7;
    int quad = lane >> 4, m = lane & 15;
    int k = ks * 32 + quad * 8 + j, n = nt * 16 + m;
    float v = (k < 265) ? Qw1[k * HID + n] : 0.0f;
    w3f[i3] = f2bf(v);
    return;
  }
  int i4 = i3 - 73728;
  if (i4 < 8192) {                          // Qw2 as B
    int ks = i4 >> 10, r = i4 & 1023;
    int nt = r >> 9, r2 = r & 511, lane = r2 >> 3, j = r2 & 7;
    int quad = lane >> 4, m = lane & 15;
    int k = ks * 32 + quad * 8 + j, n = nt * 16 + m;
    float v = (n < ADIM) ? Qw2[k * ADIM + n] : 0.0f;
    wq2f[i4] = f2bf(v);
  }
}

// ---------------------------------------------------------------------------
// K1: fused encoder + pool. NB=2 elems, 8 waves (512 thr), R2 structure +
// (a) A16 dedup (A16 == A[e=we][mtA=g], selected by wave-uniform branch)
// (b) b2 folded into K (k=256 validity row in h, b2 row in w2f): removes
//     ballot/ninv machinery and 68 epilogue v_adds; invalid agents exact 0.
// Goal: arch VGPR <= 60 so arch+acc(68) <= 128 -> 4 waves/SIMD (was 132 -> 3).
// hlds layout: [(e*4+g)*9 + ks][lane][j] bf16, ks=0..8 (ks 8 = validity row).
// ---------------------------------------------------------------------------
__global__ __launch_bounds__(512, 4)
void k_enc(const float* __restrict__ s, const short* __restrict__ w1f,
           const short* __restrict__ w2f, float* __restrict__ so288, int B) {
  __shared__ __align__(16) short hlds[36864];  // 72 KB
  __shared__ float red8[8];

  const int tid = threadIdx.x;
  const int w = tid >> 6, lane = tid & 63;
  const int q = lane >> 4, m = lane & 15;
  const int we = w >> 2, g = w & 3;
  const size_t bg0 = 2 * (size_t)blockIdx.x;
  size_t bg = bg0 + we; if (bg >= (size_t)B) bg = B - 1;

  // ---- phase 1: h = relu([surr,1]@[W1;b1]) for agents 16g..16g+15 of elem we
  const float* srow0 = s + bg * SROW + CAR;
  int4 pk = {0, 0, 0, 0};
  bool inv = false;
  if (lane < 16) {                           // agent = 16*g + lane
    const float* sr = srow0 + (g * 16 + lane) * CAR;
    float4 f0 = ((const float4*)sr)[0], f1 = ((const float4*)sr)[1];
    inv = (f0.x == -1.f) | (f0.y == -1.f) | (f0.z == -1.f) | (f0.w == -1.f) |
          (f1.x == -1.f) | (f1.y == -1.f) | (f1.z == -1.f) | (f1.w == -1.f);
    if (!inv) {                              // mask folded at source
      pk.x = (int)f2bf2(f0.x, f0.y); pk.y = (int)f2bf2(f0.z, f0.w);
      pk.z = (int)f2bf2(f1.x, f1.y); pk.w = (int)f2bf2(f1.z, f1.w);
    }
  }
  const float vflag = inv ? 0.f : 1.f;

  if (w == 1 || w == 2) {                    // self-state + tail pad per elem
    size_t rr = bg0 + (w - 1); if (rr >= (size_t)B) rr = B - 1;
    if (lane < CAR)       so288[rr * XPAD + lane] = s[rr * SROW + lane];
    else if (lane < 16)   so288[rr * XPAD + 280 + (lane - 8)] = 0.f;
  }

  int4 p0;
  p0.x = __shfl(pk.x, m, 64); p0.y = __shfl(pk.y, m, 64);
  p0.z = __shfl(pk.z, m, 64); p0.w = __shfl(pk.w, m, 64);
  const float vv0 = __shfl(vflag, m, 64);
  if (q == 1) {                              // k=8 constant-1 column (masked)
    p0.x = (vv0 != 0.f) ? 0x3f80 : 0; p0.y = p0.z = p0.w = 0;
  } else if (q >= 2) {
    p0.x = p0.y = p0.z = p0.w = 0;
  }
  sh8 bs = __builtin_bit_cast(sh8, p0);

  const int sbase = (we * 4 + g) * 9;
#pragma unroll 4
  for (int mt = 0; mt < 16; ++mt) {
    sh8 af = *(const sh8*)(w1f + (mt * 64 + lane) * 8);
    f32x4 z = {0.f, 0.f, 0.f, 0.f};
    f32x4 c0 = __builtin_amdgcn_mfma_f32_16x16x32_bf16(af, bs, z, 0, 0, 0);
    const int hidb = mt * 16 + q * 4;
    const int ks = hidb >> 5, qB = (hidb >> 3) & 3, js = hidb & 7;
    uint2 k0;
    k0.x = pkt(fmaxf(c0[0], 0.f), fmaxf(c0[1], 0.f));
    k0.y = pkt(fmaxf(c0[2], 0.f), fmaxf(c0[3], 0.f));
    *(uint2*)(&hlds[(sbase + ks) * 512 + (qB * 16 + m) * 8 + js]) = k0;
  }
  {                                          // ks=8 validity row: k=256 -> vflag
    int4 ov = {(q == 0 && vv0 != 0.f) ? 0x3f80 : 0, 0, 0, 0};
    *(int4*)(&hlds[(sbase + 8) * 512 + lane * 8]) = ov;
  }
  __syncthreads();

  // ---- phase 2: enc_acc = [h,v] @ [W2;b2], tiles {2w,2w+1} both elems ----
  f32x4 acc[4][2][2];                        // [mtA][i][e]
  f32x4 acc16 = {0.f, 0.f, 0.f, 0.f};
#pragma unroll
  for (int mtA = 0; mtA < 4; ++mtA)
#pragma unroll
    for (int i = 0; i < 2; ++i)
#pragma unroll
      for (int e = 0; e < 2; ++e) {
        f32x4 z = {0.f, 0.f, 0.f, 0.f};
        acc[mtA][i][e] = z;
      }
  const int t0 = 2 * w;
#pragma unroll
  for (int ks = 0; ks < 9; ++ks) {
    sh8 B0  = *(const sh8*)(w2f + ((ks * 17 + t0)     * 64 + lane) * 8);
    sh8 B1  = *(const sh8*)(w2f + ((ks * 17 + t0 + 1) * 64 + lane) * 8);
    sh8 B16 = *(const sh8*)(w2f + ((ks * 17 + 16)     * 64 + lane) * 8);
#pragma unroll
    for (int e = 0; e < 2; ++e) {
      sh8 A0 = *(const sh8*)(&hlds[((e * 4 + 0) * 9 + ks) * 512 + lane * 8]);
      sh8 A1 = *(const sh8*)(&hlds[((e * 4 + 1) * 9 + ks) * 512 + lane * 8]);
      sh8 A2 = *(const sh8*)(&hlds[((e * 4 + 2) * 9 + ks) * 512 + lane * 8]);
      sh8 A3 = *(const sh8*)(&hlds[((e * 4 + 3) * 9 + ks) * 512 + lane * 8]);
      acc[0][0][e] = __builtin_amdgcn_mfma_f32_16x16x32_bf16(A0, B0, acc[0][0][e], 0, 0, 0);
      acc[1][0][e] = __builtin_amdgcn_mfma_f32_16x16x32_bf16(A1, B0, acc[1][0][e], 0, 0, 0);
      acc[2][0][e] = __builtin_amdgcn_mfma_f32_16x16x32_bf16(A2, B0, acc[2][0][e], 0, 0, 0);
      acc[3][0][e] = __builtin_amdgcn_mfma_f32_16x16x32_bf16(A3, B0, acc[3][0][e], 0, 0, 0);
      acc[0][1][e] = __builtin_amdgcn_mfma_f32_16x16x32_bf16(A0, B1, acc[0][1][e], 0, 0, 0);
      acc[1][1][e] = __builtin_amdgcn_mfma_f32_16x16x32_bf16(A1, B1, acc[1][1][e], 0, 0, 0);
      acc[2][1][e] = __builtin_amdgcn_mfma_f32_16x16x32_bf16(A2, B1, acc[2][1][e], 0, 0, 0);
      acc[3][1][e] = __builtin_amdgcn_mfma_f32_16x16x32_bf16(A3, B1, acc[3][1][e], 0, 0, 0);
      if (we == e) {                         // A16 dedup: A16 == A[g]
        if (g == 0)      acc16 = __builtin_amdgcn_mfma_f32_16x16x32_bf16(A0, B16, acc16, 0, 0, 0);
        else if (g == 1) acc16 = __builtin_amdgcn_mfma_f32_16x16x32_bf16(A1, B16, acc16, 0, 0, 0);
        else if (g == 2) acc16 = __builtin_amdgcn_mfma_f32_16x16x32_bf16(A2, B16, acc16, 0, 0, 0);
        else             acc16 = __builtin_amdgcn_mfma_f32_16x16x32_bf16(A3, B16, acc16, 0, 0, 0);
      }
    }
  }

  // ---- phase 3: relu + pool (bias already inside acc; invalid rows exact 0)
  size_t rr0 = bg0;     if (rr0 >= (size_t)B) rr0 = B - 1;
  size_t rr1 = bg0 + 1; if (rr1 >= (size_t)B) rr1 = B - 1;
#pragma unroll
  for (int i = 0; i < 2; ++i) {
    const int col = (t0 + i) * 16 + m;       // 0..255
#pragma unroll
    for (int e = 0; e < 2; ++e) {
      float ssum = 0.f;
#pragma unroll
      for (int mtA = 0; mtA < 4; ++mtA)
#pragma unroll
        for (int r = 0; r < 4; ++r)
          ssum += fmaxf(acc[mtA][i][e][r], 0.f);
      ssum += __shfl_xor(ssum, 16, 64);
      ssum += __shfl_xor(ssum, 32, 64);
      if (q == 0)
        so288[(e ? rr1 : rr0) * XPAD + CAR + col] = ssum;
    }
  }
  // col-256 tile: per-wave 16-agent partial, cross-wave via red8
  {
    float s16 = 0.f;
#pragma unroll
    for (int r = 0; r < 4; ++r) s16 += fmaxf(acc16[r], 0.f);
    s16 += __shfl_xor(s16, 16, 64);
    s16 += __shfl_xor(s16, 32, 64);
    if (lane == 0) red8[w] = s16;
  }
  __syncthreads();
  if ((w == 0 || w == 4) && lane < 16) {     // wave 0 -> elem 0, wave 4 -> elem 1
    const int e2 = w >> 2;
    size_t rr2 = bg0 + e2; if (rr2 >= (size_t)B) rr2 = B - 1;
    float v = 0.f;
    if (lane == 0)
      v = red8[4 * e2] + red8[4 * e2 + 1] + red8[4 * e2 + 2] + red8[4 * e2 + 3];
    so288[rr2 * XPAD + CAR + 256 + lane] = v;  // lanes 1..15 zero cols 257..271
  }
}

// ---------------------------------------------------------------------------
// K2: Q-head, MFMA. 4 waves, 32 batch rows per block (unchanged, ~13 us).
// ---------------------------------------------------------------------------
__global__ __launch_bounds__(256, 2)
void k_q(const float* __restrict__ so288, const short* __restrict__ w3f,
         const float* __restrict__ Qb1, const short* __restrict__ wq2f,
         const float* __restrict__ Qb2, float* __restrict__ out, int B) {
  __shared__ __align__(16) short xf[2 * 9 * 64 * 8];  // 36 KB, [mt][ks][lane][j]
  __shared__ __align__(16) float H[32 * 260];          // 33.3 KB
  const int tid = threadIdx.x;
  const int w = tid >> 6, lane = tid & 63;
  const int q = lane >> 4, m = lane & 15;
  const int b0 = blockIdx.x * 32;

  // ---- stage X ----
#pragma unroll
  for (int it = 0; it < 5; ++it) {
    int sidx = tid + it * 256;               // = (mt*9+ks)*64 + l
    if (sidx < 1152) {
      int mt = sidx / 576, rem = sidx % 576;
      int ks = rem >> 6, l = rem & 63;
      int lq = l >> 4, lm = l & 15;
      int row = b0 + mt * 16 + lm; if (row >= B) row = B - 1;
      const float* xp = so288 + (size_t)row * XPAD + ks * 32 + lq * 8;
      float4 xa = ((const float4*)xp)[0], xb = ((const float4*)xp)[1];
      int4 t = {(int)f2bf2(xa.x, xa.y), (int)f2bf2(xa.z, xa.w),
                (int)f2bf2(xb.x, xb.y), (int)f2bf2(xb.z, xb.w)};
      *(int4*)(xf + sidx * 8) = t;
    }
  }
  __syncthreads();

  // ---- GEMM1: X(32x288) @ Qw1 -> H ----
  f32x4 acc1[2][4];
#pragma unroll
  for (int mt = 0; mt < 2; ++mt)
#pragma unroll
    for (int i = 0; i < 4; ++i) {
      f32x4 z = {0.f, 0.f, 0.f, 0.f};
      acc1[mt][i] = z;
    }
#pragma unroll
  for (int ks = 0; ks < 9; ++ks) {
    sh8 A0 = *(const sh8*)(xf + ((0 * 9 + ks) * 64 + lane) * 8);
    sh8 A1 = *(const sh8*)(xf + ((1 * 9 + ks) * 64 + lane) * 8);
#pragma unroll
    for (int i = 0; i < 4; ++i) {
      sh8 Bf = *(const sh8*)(w3f + ((ks * 16 + 4 * w + i) * 64 + lane) * 8);
      acc1[0][i] = __builtin_amdgcn_mfma_f32_16x16x32_bf16(A0, Bf, acc1[0][i], 0, 0, 0);
      acc1[1][i] = __builtin_amdgcn_mfma_f32_16x16x32_bf16(A1, Bf, acc1[1][i], 0, 0, 0);
    }
  }
#pragma unroll
  for (int i = 0; i < 4; ++i) {
    const int hcol = (4 * w + i) * 16 + m;
    const float bq = Qb1[hcol];
#pragma unroll
    for (int mt = 0; mt < 2; ++mt)
#pragma unroll
      for (int r = 0; r < 4; ++r)
        H[(mt * 16 + q * 4 + r) * 260 + hcol] = fmaxf(acc1[mt][i][r] + bq, 0.f);
  }
  __syncthreads();

  // ---- GEMM2: H(32x256) @ Qw2 -> out ----
  const int mt2 = w >> 1, nt2 = w & 1;
  f32x4 acc2 = {0.f, 0.f, 0.f, 0.f};
#pragma unroll
  for (int ks = 0; ks < 8; ++ks) {
    const float* hp = H + (mt2 * 16 + m) * 260 + ks * 32 + q * 8;
    float4 ha = ((const float4*)hp)[0], hb = ((const float4*)hp)[1];
    int4 t = {(int)f2bf2(ha.x, ha.y), (int)f2bf2(ha.z, ha.w),
              (int)f2bf2(hb.x, hb.y), (int)f2bf2(hb.z, hb.w)};
    sh8 A2 = __builtin_bit_cast(sh8, t);
    sh8 Bf = *(const sh8*)(wq2f + ((ks * 2 + nt2) * 64 + lane) * 8);
    acc2 = __builtin_amdgcn_mfma_f32_16x16x32_bf16(A2, Bf, acc2, 0, 0, 0);
  }
  const int act = nt2 * 16 + m;
  if (act < ADIM) {
    const float bq = Qb2[act];
#pragma unroll
    for (int r = 0; r < 4; ++r) {
      const int row = b0 + mt2 * 16 + q * 4 + r;
      if (row < B) out[(size_t)row * ADIM + act] = acc2[r] + bq;
    }
  }
}

extern "C" void kernel_launch(void* const* d_in, const int* in_sizes, int n_in,
                              void* d_out, int out_size, void* d_ws, size_t ws_size,
                              hipStream_t stream) {
  const float* s   = (const float*)d_in[0];
  const float* W1  = (const float*)d_in[1];
  const float* b1  = (const float*)d_in[2];
  const float* W2  = (const float*)d_in[3];
  const float* b2  = (const float*)d_in[4];
  const float* Qw1 = (const float*)d_in[5];
  const float* Qb1 = (const float*)d_in[6];
  const float* Qw2 = (const float*)d_in[7];
  const float* Qb2 = (const float*)d_in[8];
  float* out = (float*)d_out;
  const int B = in_sizes[0] / SROW;

  // ws: [so288: B*288 f32][w1f 8192][w2f 78336][w3f 73728][wq2f 8192] bf16
  char* wsb = (char*)d_ws;
  float* so288 = (float*)wsb;
  size_t off = (size_t)B * XPAD * sizeof(float);
  short* w1f  = (short*)(wsb + off);            off += 8192 * 2;
  short* w2f  = (short*)(wsb + off);            off += 78336 * 2;
  short* w3f  = (short*)(wsb + off);            off += 73728 * 2;
  short* wq2f = (short*)(wsb + off);

  const int prep_elems = 8192 + 78336 + 73728 + 8192;
  k_prep<<<(prep_elems + 255) / 256, 256, 0, stream>>>(W1, b1, W2, b2, Qw1, Qw2,
                                                       w1f, w2f, w3f, wq2f);
  k_enc<<<(B + 1) / 2, 512, 0, stream>>>(s, w1f, w2f, so288, B);
  k_q<<<(B + 31) / 32, 256, 0, stream>>>(so288, w3f, Qb1, wq2f, Qb2, out, B);
}

// Round 6
// 162.651 us; speedup vs baseline: 1.0354x; 1.0301x over previous
//
#include <hip/hip_runtime.h>

#define CAR 8
#define SROW 520   // CAR + 64*CAR
#define HID 256
#define EOUT 257
#define XPAD 288   // padded Q-input row: 8 self + 257 enc + pad, 9 k-steps of 32
#define ADIM 30

typedef __attribute__((ext_vector_type(8))) short sh8;
typedef __attribute__((ext_vector_type(4))) float f32x4;

__device__ __forceinline__ short f2bf(float f) {
  unsigned u = __builtin_bit_cast(unsigned, f);
  u += 0x7fffu + ((u >> 16) & 1u);   // RNE
  return (short)(u >> 16);
}
// pack two fp32 -> packed bf16x2 (RNE, 5 VALU)
__device__ __forceinline__ unsigned f2bf2(float a, float b) {
  unsigned ua = __builtin_bit_cast(unsigned, a);
  ua += 0x7fffu + ((ua >> 16) & 1u);
  unsigned ub = __builtin_bit_cast(unsigned, b);
  ub += 0x7fffu + ((ub >> 16) & 1u);
  return __builtin_amdgcn_perm(ub, ua, 0x07060302);  // [a | b<<16]
}
// pack two fp32 -> packed bf16x2 (TRUNC, 1 VALU) — used for h staging only
__device__ __forceinline__ unsigned pkt(float a, float b) {
  return __builtin_amdgcn_perm(__builtin_bit_cast(unsigned, b),
                               __builtin_bit_cast(unsigned, a), 0x07060302);
}

// ---------------------------------------------------------------------------
// Prep: swizzle all weights to bf16 MFMA fragments. (R2-verbatim, verified)
// w1f : [W1;b1]^T as A [16 mt][64][8]  k=0..7 -> W1 row, k=8 -> b1   (8192)
// w2f : W2  as B   [8 ks][17 nt][64][8]               (69632)  stride/ks = 8704!
// w3f : Qw1 as B   [9 ks][16 nt][64][8], k=X-row idx  (73728)
// wq2f: Qw2 as B   [8 ks][2 nt][64][8]                (8192)
// ---------------------------------------------------------------------------
__global__ void k_prep(const float* __restrict__ W1, const float* __restrict__ b1,
                       const float* __restrict__ W2,
                       const float* __restrict__ Qw1, const float* __restrict__ Qw2,
                       short* __restrict__ w1f, short* __restrict__ w2f,
                       short* __restrict__ w3f, short* __restrict__ wq2f) {
  int idx = blockIdx.x * 256 + threadIdx.x;
  if (idx < 8192) {                         // [W1;b1]^T as A
    int mt = idx >> 9, r = idx & 511, lane = r >> 3, j = r & 7;
    int quad = lane >> 4, m = lane & 15;
    int hid = mt * 16 + m;
    float v = (quad == 0) ? W1[j * HID + hid]
            : (quad == 1 && j == 0) ? b1[hid] : 0.0f;   // k=8 row = b1
    w1f[idx] = f2bf(v);
    return;
  }
  int i2 = idx - 8192;
  if (i2 < 69632) {                         // W2 as B (ks stride = 17*512 = 8704)
    int ks = i2 / 8704, r = i2 % 8704;
    int nt = r >> 9, r2 = r & 511, lane = r2 >> 3, j = r2 & 7;
    int quad = lane >> 4, m = lane & 15;
    int k = ks * 32 + quad * 8 + j, n = nt * 16 + m;
    float v = (n < EOUT) ? W2[k * EOUT + n] : 0.0f;
    w2f[i2] = f2bf(v);
    return;
  }
  int i3 = i2 - 69632;
  if (i3 < 73728) {                         // Qw1 as B (k indexes padded X row)
    int ks = i3 >> 13, r = i3 & 8191;
    int nt = r >> 9, r2 = r & 511, lane = r2 >> 3, j = r2 & 7;
    int quad = lane >> 4, m = lane & 15;
    int k = ks * 32 + quad * 8 + j, n = nt * 16 + m;
    float v = (k < 265) ? Qw1[k * HID + n] : 0.0f;
    w3f[i3] = f2bf(v);
    return;
  }
  int i4 = i3 - 73728;
  if (i4 < 8192) {                          // Qw2 as B
    int ks = i4 >> 10, r = i4 & 1023;
    int nt = r >> 9, r2 = r & 511, lane = r2 >> 3, j = r2 & 7;
    int quad = lane >> 4, m = lane & 15;
    int k = ks * 32 + quad * 8 + j, n = nt * 16 + m;
    float v = (n < ADIM) ? Qw2[k * ADIM + n] : 0.0f;
    wq2f[i4] = f2bf(v);
  }
}

// ---------------------------------------------------------------------------
// K1: fused encoder + pool. NB=2 elems, 8 waves (512 thr). R2-verified base +
// (a) A16-dedup (R4-verified): acc16 reuses A[g] instead of a 9th ds_read.
// (b) bias-as-C-init: acc starts at b2[col] (C-operand accumulate) — removes
//     68 epilogue v_adds; math identical.
// (c) s_setprio(1) around the MFMA cluster (T5; independent small blocks =
//     the regime where it measured +4-7%).
// Wave w: elem we=w>>2, agent group g=w&3; phase 2 tiles {2w, 2w+1}.
// ---------------------------------------------------------------------------
__global__ __launch_bounds__(512, 4)
void k_enc(const float* __restrict__ s, const short* __restrict__ w1f,
           const short* __restrict__ w2f, const float* __restrict__ b2,
           float* __restrict__ so288, int B) {
  __shared__ __align__(16) short hlds[2][16384];  // 64 KB: [e][(g*8+ks)*64+slot]*8+j
  __shared__ float ninvp[8];
  __shared__ float t16[8][16];

  const int tid = threadIdx.x;
  const int w = tid >> 6, lane = tid & 63;
  const int q = lane >> 4, m = lane & 15;
  const int we = w >> 2, g = w & 3;
  const size_t bg0 = 2 * (size_t)blockIdx.x;
  size_t bg = bg0 + we; if (bg >= (size_t)B) bg = B - 1;

  // ---- phase 1: h = relu([surr,1]@[W1;b1]) for 16 agents (g) of elem we ----
  const float* srow0 = s + bg * SROW + CAR;
  int4 pk = {0, 0, 0, 0};
  bool inv = false;
  if (lane < 16) {                           // agent = 16*g + lane
    const float* sr = srow0 + (g * 16 + lane) * CAR;
    float4 f0 = ((const float4*)sr)[0], f1 = ((const float4*)sr)[1];
    inv = (f0.x == -1.f) | (f0.y == -1.f) | (f0.z == -1.f) | (f0.w == -1.f) |
          (f1.x == -1.f) | (f1.y == -1.f) | (f1.z == -1.f) | (f1.w == -1.f);
    if (!inv) {                              // mask folded at source
      pk.x = (int)f2bf2(f0.x, f0.y); pk.y = (int)f2bf2(f0.z, f0.w);
      pk.z = (int)f2bf2(f1.x, f1.y); pk.w = (int)f2bf2(f1.z, f1.w);
    }
  }
  const float vflag = inv ? 0.f : 1.f;
  unsigned long long bal = __ballot(inv);
  if (lane == 0) ninvp[w] = (float)__popcll(bal);

  if (w == 1 || w == 2) {                    // self-state + tail pad per elem
    size_t rr = bg0 + (w - 1); if (rr >= (size_t)B) rr = B - 1;
    if (lane < CAR)       so288[rr * XPAD + lane] = s[rr * SROW + lane];
    else if (lane < 16)   so288[rr * XPAD + 280 + (lane - 8)] = 0.f;
  }

  int4 p0;
  p0.x = __shfl(pk.x, m, 64); p0.y = __shfl(pk.y, m, 64);
  p0.z = __shfl(pk.z, m, 64); p0.w = __shfl(pk.w, m, 64);
  const float vv0 = __shfl(vflag, m, 64);
  if (q == 1) {                              // k=8 constant-1 column (masked)
    p0.x = (vv0 != 0.f) ? 0x3f80 : 0; p0.y = p0.z = p0.w = 0;
  } else if (q >= 2) {
    p0.x = p0.y = p0.z = p0.w = 0;
  }
  sh8 bs = __builtin_bit_cast(sh8, p0);

#pragma unroll 4
  for (int mt = 0; mt < 16; ++mt) {
    sh8 af = *(const sh8*)(w1f + (mt * 64 + lane) * 8);
    f32x4 z = {0.f, 0.f, 0.f, 0.f};
    f32x4 c0 = __builtin_amdgcn_mfma_f32_16x16x32_bf16(af, bs, z, 0, 0, 0);
    const int hidb = mt * 16 + q * 4;
    const int ks = hidb >> 5, qB = (hidb >> 3) & 3, js = hidb & 7;
    uint2 k0;
    k0.x = pkt(fmaxf(c0[0], 0.f), fmaxf(c0[1], 0.f));
    k0.y = pkt(fmaxf(c0[2], 0.f), fmaxf(c0[3], 0.f));
    *(uint2*)(&hlds[we][((g * 8 + ks) * 64 + qB * 16 + m) * 8 + js]) = k0;
  }
  __syncthreads();

  // ---- phase 2: enc = h @ W2, tiles {2w, 2w+1} both elems + dedup'd tile16 -
  const int t0 = 2 * w;
  const float bi0  = b2[t0 * 16 + m];        // bias as C-init (col-indexed)
  const float bi1  = b2[t0 * 16 + 16 + m];
  const float bi16 = (m == 0) ? b2[256] : 0.f;
  f32x4 acc[4][2][2];                        // [mtA][i][e]
  f32x4 acc16 = {bi16, bi16, bi16, bi16};
#pragma unroll
  for (int mtA = 0; mtA < 4; ++mtA)
#pragma unroll
    for (int e = 0; e < 2; ++e) {
      f32x4 c0 = {bi0, bi0, bi0, bi0};
      f32x4 c1 = {bi1, bi1, bi1, bi1};
      acc[mtA][0][e] = c0;
      acc[mtA][1][e] = c1;
    }
#pragma unroll
  for (int ks = 0; ks < 8; ++ks) {
    sh8 B0  = *(const sh8*)(w2f + ((ks * 17 + t0)     * 64 + lane) * 8);
    sh8 B1  = *(const sh8*)(w2f + ((ks * 17 + t0 + 1) * 64 + lane) * 8);
    sh8 B16 = *(const sh8*)(w2f + ((ks * 17 + 16)     * 64 + lane) * 8);
#pragma unroll
    for (int e = 0; e < 2; ++e) {
      sh8 A0 = *(const sh8*)(&hlds[e][(0 * 8 + ks) * 512 + lane * 8]);
      sh8 A1 = *(const sh8*)(&hlds[e][(1 * 8 + ks) * 512 + lane * 8]);
      sh8 A2 = *(const sh8*)(&hlds[e][(2 * 8 + ks) * 512 + lane * 8]);
      sh8 A3 = *(const sh8*)(&hlds[e][(3 * 8 + ks) * 512 + lane * 8]);
      __builtin_amdgcn_s_setprio(1);
      acc[0][0][e] = __builtin_amdgcn_mfma_f32_16x16x32_bf16(A0, B0, acc[0][0][e], 0, 0, 0);
      acc[1][0][e] = __builtin_amdgcn_mfma_f32_16x16x32_bf16(A1, B0, acc[1][0][e], 0, 0, 0);
      acc[2][0][e] = __builtin_amdgcn_mfma_f32_16x16x32_bf16(A2, B0, acc[2][0][e], 0, 0, 0);
      acc[3][0][e] = __builtin_amdgcn_mfma_f32_16x16x32_bf16(A3, B0, acc[3][0][e], 0, 0, 0);
      acc[0][1][e] = __builtin_amdgcn_mfma_f32_16x16x32_bf16(A0, B1, acc[0][1][e], 0, 0, 0);
      acc[1][1][e] = __builtin_amdgcn_mfma_f32_16x16x32_bf16(A1, B1, acc[1][1][e], 0, 0, 0);
      acc[2][1][e] = __builtin_amdgcn_mfma_f32_16x16x32_bf16(A2, B1, acc[2][1][e], 0, 0, 0);
      acc[3][1][e] = __builtin_amdgcn_mfma_f32_16x16x32_bf16(A3, B1, acc[3][1][e], 0, 0, 0);
      if (we == e) {                         // A16 dedup: A16 == A[g]
        if (g == 0)      acc16 = __builtin_amdgcn_mfma_f32_16x16x32_bf16(A0, B16, acc16, 0, 0, 0);
        else if (g == 1) acc16 = __builtin_amdgcn_mfma_f32_16x16x32_bf16(A1, B16, acc16, 0, 0, 0);
        else if (g == 2) acc16 = __builtin_amdgcn_mfma_f32_16x16x32_bf16(A2, B16, acc16, 0, 0, 0);
        else             acc16 = __builtin_amdgcn_mfma_f32_16x16x32_bf16(A3, B16, acc16, 0, 0, 0);
      }
      __builtin_amdgcn_s_setprio(0);
    }
  }

  // ---- phase 3: relu + masked pool (bias already in acc via C-init) ----
  const float ninv[2] = {ninvp[0] + ninvp[1] + ninvp[2] + ninvp[3],
                         ninvp[4] + ninvp[5] + ninvp[6] + ninvp[7]};
#pragma unroll
  for (int i = 0; i < 2; ++i) {
    const int col = (t0 + i) * 16 + m;       // 0..255, always < EOUT
    const float bic = (i == 0) ? bi0 : bi1;
    const float rb2 = fmaxf(bic, 0.f);
#pragma unroll
    for (int e = 0; e < 2; ++e) {
      float ssum = 0.f;
#pragma unroll
      for (int mtA = 0; mtA < 4; ++mtA)
#pragma unroll
        for (int r = 0; r < 4; ++r)
          ssum += fmaxf(acc[mtA][i][e][r], 0.f);
      ssum += __shfl_xor(ssum, 16, 64);
      ssum += __shfl_xor(ssum, 32, 64);
      ssum -= ninv[e] * rb2;                 // invalid agents contribute relu(b2)
      if (q == 0) {
        size_t rr = bg0 + e; if (rr >= (size_t)B) rr = B - 1;
        so288[rr * XPAD + CAR + col] = ssum;
      }
    }
  }
  // tile 16 (cols 256..271): per-wave partial (16 agents of elem we)
  {
    float s16 = 0.f;
#pragma unroll
    for (int r = 0; r < 4; ++r)
      s16 += fmaxf(acc16[r], 0.f);
    s16 += __shfl_xor(s16, 16, 64);
    s16 += __shfl_xor(s16, 32, 64);
    if (q == 0) t16[w][m] = s16;
  }
  __syncthreads();
  if ((w == 0 || w == 4) && q == 0) {        // wave 0 -> elem 0, wave 4 -> elem 1
    const int e2 = w >> 2;
    const float b2c = (m == 0) ? b2[256] : 0.f;
    const float tot = t16[e2 * 4 + 0][m] + t16[e2 * 4 + 1][m] +
                      t16[e2 * 4 + 2][m] + t16[e2 * 4 + 3][m]
                    - ninv[e2] * fmaxf(b2c, 0.f);  // pad cols: all terms 0
    size_t rr2 = bg0 + e2; if (rr2 >= (size_t)B) rr2 = B - 1;
    so288[rr2 * XPAD + CAR + 256 + m] = tot;
  }
}

// ---------------------------------------------------------------------------
// K2: Q-head, MFMA. 4 waves, 16 batch rows per block (512 blocks -> 2/CU,
// halves the exposed per-block latency chain; LDS 26 KB).
// ---------------------------------------------------------------------------
__global__ __launch_bounds__(256, 2)
void k_q(const float* __restrict__ so288, const short* __restrict__ w3f,
         const float* __restrict__ Qb1, const short* __restrict__ wq2f,
         const float* __restrict__ Qb2, float* __restrict__ out, int B) {
  __shared__ __align__(16) short xf[9 * 64 * 8];  // 9.2 KB, [ks][lane][j]
  __shared__ __align__(16) float H[16 * 260];      // 16.6 KB
  const int tid = threadIdx.x;
  const int w = tid >> 6, lane = tid & 63;
  const int q = lane >> 4, m = lane & 15;
  const int b0 = blockIdx.x * 16;

  // ---- stage X (16 rows x 9 k-steps) ----
#pragma unroll
  for (int it = 0; it < 3; ++it) {
    int sidx = tid + it * 256;               // = ks*64 + l
    if (sidx < 576) {
      int ks = sidx >> 6, l = sidx & 63;
      int lq = l >> 4, lm = l & 15;
      int row = b0 + lm; if (row >= B) row = B - 1;
      const float* xp = so288 + (size_t)row * XPAD + ks * 32 + lq * 8;
      float4 xa = ((const float4*)xp)[0], xb = ((const float4*)xp)[1];
      int4 t = {(int)f2bf2(xa.x, xa.y), (int)f2bf2(xa.z, xa.w),
                (int)f2bf2(xb.x, xb.y), (int)f2bf2(xb.z, xb.w)};
      *(int4*)(xf + sidx * 8) = t;
    }
  }
  __syncthreads();

  // ---- GEMM1: X(16x288) @ Qw1 -> H ----
  f32x4 acc1[4];
#pragma unroll
  for (int i = 0; i < 4; ++i) {
    f32x4 z = {0.f, 0.f, 0.f, 0.f};
    acc1[i] = z;
  }
#pragma unroll
  for (int ks = 0; ks < 9; ++ks) {
    sh8 A0 = *(const sh8*)(xf + (ks * 64 + lane) * 8);
#pragma unroll
    for (int i = 0; i < 4; ++i) {
      sh8 Bf = *(const sh8*)(w3f + ((ks * 16 + 4 * w + i) * 64 + lane) * 8);
      acc1[i] = __builtin_amdgcn_mfma_f32_16x16x32_bf16(A0, Bf, acc1[i], 0, 0, 0);
    }
  }
#pragma unroll
  for (int i = 0; i < 4; ++i) {
    const int hcol = (4 * w + i) * 16 + m;
    const float bq = Qb1[hcol];
#pragma unroll
    for (int r = 0; r < 4; ++r)
      H[(q * 4 + r) * 260 + hcol] = fmaxf(acc1[i][r] + bq, 0.f);
  }
  __syncthreads();

  // ---- GEMM2: H(16x256) @ Qw2 -> out (waves 0,1) ----
  if (w < 2) {
    f32x4 acc2 = {0.f, 0.f, 0.f, 0.f};
#pragma unroll
    for (int ks = 0; ks < 8; ++ks) {
      const float* hp = H + m * 260 + ks * 32 + q * 8;
      float4 ha = ((const float4*)hp)[0], hb = ((const float4*)hp)[1];
      int4 t = {(int)f2bf2(ha.x, ha.y), (int)f2bf2(ha.z, ha.w),
                (int)f2bf2(hb.x, hb.y), (int)f2bf2(hb.z, hb.w)};
      sh8 A2 = __builtin_bit_cast(sh8, t);
      sh8 Bf = *(const sh8*)(wq2f + ((ks * 2 + w) * 64 + lane) * 8);
      acc2 = __builtin_amdgcn_mfma_f32_16x16x32_bf16(A2, Bf, acc2, 0, 0, 0);
    }
    const int act = w * 16 + m;
    if (act < ADIM) {
      const float bq = Qb2[act];
#pragma unroll
      for (int r = 0; r < 4; ++r) {
        const int row = b0 + q * 4 + r;
        if (row < B) out[(size_t)row * ADIM + act] = acc2[r] + bq;
      }
    }
  }
}

extern "C" void kernel_launch(void* const* d_in, const int* in_sizes, int n_in,
                              void* d_out, int out_size, void* d_ws, size_t ws_size,
                              hipStream_t stream) {
  const float* s   = (const float*)d_in[0];
  const float* W1  = (const float*)d_in[1];
  const float* b1  = (const float*)d_in[2];
  const float* W2  = (const float*)d_in[3];
  const float* b2  = (const float*)d_in[4];
  const float* Qw1 = (const float*)d_in[5];
  const float* Qb1 = (const float*)d_in[6];
  const float* Qw2 = (const float*)d_in[7];
  const float* Qb2 = (const float*)d_in[8];
  float* out = (float*)d_out;
  const int B = in_sizes[0] / SROW;

  // ws: [so288: B*288 f32][w1f 8192][w2f 69632][w3f 73728][wq2f 8192] bf16
  char* wsb = (char*)d_ws;
  float* so288 = (float*)wsb;
  size_t off = (size_t)B * XPAD * sizeof(float);
  short* w1f  = (short*)(wsb + off);            off += 8192 * 2;
  short* w2f  = (short*)(wsb + off);            off += 69632 * 2;
  short* w3f  = (short*)(wsb + off);            off += 73728 * 2;
  short* wq2f = (short*)(wsb + off);

  const int prep_elems = 8192 + 69632 + 73728 + 8192;
  k_prep<<<(prep_elems + 255) / 256, 256, 0, stream>>>(W1, b1, W2, Qw1, Qw2,
                                                       w1f, w2f, w3f, wq2f);
  k_enc<<<(B + 1) / 2, 512, 0, stream>>>(s, w1f, w2f, b2, so288, B);
  k_q<<<(B + 15) / 16, 256, 0, stream>>>(so288, w3f, Qb1, wq2f, Qb2, out, B);
}